// Round 6
// baseline (86.829 us; speedup 1.0000x reference)
//
#include <hip/hip_runtime.h>
#include <hip/hip_bf16.h>

// Problem constants
#define B_DIM   32768
#define A_DIM   64
#define L_DIM   1024          // K
#define N_COLS  128           // 2*A

using bf16x8 = __attribute__((ext_vector_type(8))) __bf16;
using f32x4  = __attribute__((ext_vector_type(4))) float;

// ---------------------------------------------------------------------------
// Pre-kernel: convert W [128 x 1024] f32 -> bf16 in MFMA B-fragment order.
// Unit v (16B): nl=v&15, sub=(v>>4)&3, cf=(v>>6)&7, ks=(v>>9)&31
//   holds Wm[n = cf*16+nl][k = ks*32 + sub*8 + i], i=0..7
// ---------------------------------------------------------------------------
__global__ __launch_bounds__(256)
void convert_w_kernel(const float* __restrict__ W, bf16x8* __restrict__ ws) {
    int v   = blockIdx.x * 256 + threadIdx.x;   // 0..16383
    int nl  = v & 15;
    int sub = (v >> 4) & 3;
    int cf  = (v >> 6) & 7;
    int ks  = (v >> 9) & 31;
    int n   = cf * 16 + nl;
    int k   = ks * 32 + sub * 8;
    const float4* wp = (const float4*)(W + (size_t)n * L_DIM + k);
    float4 w0 = wp[0];
    float4 w1 = wp[1];
    bf16x8 u;
    u[0] = (__bf16)w0.x; u[1] = (__bf16)w0.y;
    u[2] = (__bf16)w0.z; u[3] = (__bf16)w0.w;
    u[4] = (__bf16)w1.x; u[5] = (__bf16)w1.y;
    u[6] = (__bf16)w1.z; u[7] = (__bf16)w1.w;
    ws[v] = u;
}

__device__ __forceinline__ bf16x8 cvt8(float4 a, float4 b) {
    bf16x8 u;
    u[0] = (__bf16)a.x; u[1] = (__bf16)a.y; u[2] = (__bf16)a.z; u[3] = (__bf16)a.w;
    u[4] = (__bf16)b.x; u[5] = (__bf16)b.y; u[6] = (__bf16)b.z; u[7] = (__bf16)b.w;
    return u;
}

// ---------------------------------------------------------------------------
// Main kernel (split-K): 512 threads = 8 waves = 4 row-tiles x 2 k-halves.
// Block covers 64 rows x full K. Grid = 512 -> 2 blocks/CU -> 16 waves/CU.
// Wave (h, r): rows [blk*64 + r*16, +16), k in [h*512, h*512+512), all 128
// cols (acc = 8 x f32x4). B (bf16 fragment order in ws) staged per half in
// four 32 KB chunks; all LDS traffic lane-contiguous -> 0 bank conflicts.
// Split-K combine in-block: h=1 waves park acc in retired B space; h=0
// waves add + bias + tanh + store.
// ---------------------------------------------------------------------------
__global__ __launch_bounds__(512, 4)
void branched_policy_kernel(const float* __restrict__ F,
                            const float4* __restrict__ Wf,
                            const float* __restrict__ bias,
                            float* __restrict__ out) {
    __shared__ float4 ldsB[2][2048];   // 2 halves x 32 KB

    const int tid  = threadIdx.x;
    const int lane = tid & 63;
    const int wave = tid >> 6;        // 0..7
    const int h    = wave >> 2;       // k-half 0/1
    const int r    = wave & 3;        // row-tile 0..3
    const int lcol = lane & 15;       // fragment row (A) / col (B)
    const int lsub = lane >> 4;       // k subgroup 0..3
    const int blk  = blockIdx.x;
    const int tidh = tid & 255;       // index within half-group (h == tid>>8)

    const float*  fp   = F + (size_t)(blk * 64 + r * 16 + lcol) * L_DIM
                           + h * 512 + lsub * 8;
    const float4* wsrc = Wf + h * 8192 + tidh;

    f32x4 acc[8];
    #pragma unroll
    for (int cf = 0; cf < 8; ++cf) acc[cf] = (f32x4){0.f, 0.f, 0.f, 0.f};

    #pragma unroll
    for (int p = 0; p < 4; ++p) {
        // B chunk for phase p -> regs (issued before the drain barrier)
        float4 breg[8];
        #pragma unroll
        for (int i = 0; i < 8; ++i) breg[i] = wsrc[p * 2048 + i * 256];

        __syncthreads();               // prev phase's ds_reads done
        #pragma unroll
        for (int i = 0; i < 8; ++i)
            ldsB[h][i * 256 + tidh] = breg[i];     // lane-contiguous
        __syncthreads();

        // compute 4 k-steps of this phase
        #pragma unroll
        for (int j = 0; j < 4; ++j) {
            int kk = p * 4 + j;
            float4 a0 = *(const float4*)(fp + kk * 32);
            float4 a1 = *(const float4*)(fp + kk * 32 + 4);
            bf16x8 af = cvt8(a0, a1);
            #pragma unroll
            for (int cf = 0; cf < 8; ++cf) {
                bf16x8 bf = *(const bf16x8*)&ldsB[h][(j * 8 + cf) * 64 + lane];
                acc[cf] = __builtin_amdgcn_mfma_f32_16x16x32_bf16(af, bf, acc[cf], 0, 0, 0);
            }
        }
    }

    // ---- split-K combine + epilogue ----
    __syncthreads();                   // all compute ds_reads retired
    f32x4* red = (f32x4*)&ldsB[0][0];  // 32 KB, reuses retired B space
    if (h == 1) {
        #pragma unroll
        for (int cf = 0; cf < 8; ++cf)
            red[(r * 8 + cf) * 64 + lane] = acc[cf];   // lane-contiguous
    }
    __syncthreads();
    if (h == 0) {
        const int row0 = blk * 64 + r * 16 + lsub * 4;
        float* out0 = out;
        float* out1 = out + (size_t)B_DIM * A_DIM;
        #pragma unroll
        for (int cf = 0; cf < 8; ++cf) {
            f32x4 part = red[(r * 8 + cf) * 64 + lane];
            int   n  = cf * 16 + lcol;
            float bv = bias[n];
            float* ob = ((n & 1) ? out1 : out0) + (n >> 1);
            #pragma unroll
            for (int j = 0; j < 4; ++j) {
                float x = acc[cf][j] + part[j] + bv;
                float e = __expf(2.0f * x);             // tanh = 1 - 2/(e^2x+1)
                ob[(size_t)(row0 + j) * A_DIM] = 1.0f - 2.0f / (e + 1.0f);
            }
        }
    }
}

// ---------------------------------------------------------------------------
// Fallback (v1-style, self-contained) if ws is too small.
// ---------------------------------------------------------------------------
__global__ __launch_bounds__(256, 2)
void fallback_kernel(const float* __restrict__ F,
                     const float* __restrict__ W,
                     const float* __restrict__ bias,
                     float* __restrict__ out) {
    __shared__ bf16x8 ldsB[4096];
    const int tid  = threadIdx.x;
    const int lane = tid & 63;
    const int wave = tid >> 6;
    const int blk  = blockIdx.x;
    const int lcol = lane & 15;
    const int lsub = lane >> 4;
    const int arow = blk * 64 + wave * 16 + lcol;
    const float* Fp = F + (size_t)arow * L_DIM + lsub * 8;

    f32x4 acc[8];
    #pragma unroll
    for (int c = 0; c < 8; ++c) acc[c] = (f32x4){0.f, 0.f, 0.f, 0.f};

    for (int ch = 0; ch < 4; ++ch) {
        __syncthreads();
        #pragma unroll
        for (int i = 0; i < 16; ++i) {
            int v   = i * 256 + tid;
            int nl  = v & 15;
            int sub = (v >> 4) & 3;
            int c   = (v >> 6) & 7;
            int ks  = (v >> 9) & 7;
            int nn  = c * 16 + nl;
            int k   = ch * 256 + ks * 32 + sub * 8;
            const float4* wp = (const float4*)(W + (size_t)nn * L_DIM + k);
            ldsB[v] = cvt8(wp[0], wp[1]);
        }
        __syncthreads();
        #pragma unroll
        for (int ks = 0; ks < 8; ++ks) {
            const float4* ap = (const float4*)(Fp + ch * 256 + ks * 32);
            bf16x8 af = cvt8(ap[0], ap[1]);
            #pragma unroll
            for (int c = 0; c < 8; ++c) {
                bf16x8 bf = ldsB[(ks * 8 + c) * 64 + lane];
                acc[c] = __builtin_amdgcn_mfma_f32_16x16x32_bf16(af, bf, acc[c], 0, 0, 0);
            }
        }
    }

    const int orow0 = blk * 64 + wave * 16 + lsub * 4;
    float* out0 = out;
    float* out1 = out + (size_t)B_DIM * A_DIM;
    #pragma unroll
    for (int c = 0; c < 8; ++c) {
        int   nn  = c * 16 + lcol;
        float bvv = bias[nn];
        float* ob = (nn & 1) ? out1 : out0;
        #pragma unroll
        for (int j = 0; j < 4; ++j) {
            float x = acc[c][j] + bvv;
            float e = __expf(2.0f * x);
            ob[(size_t)(orow0 + j) * A_DIM + (nn >> 1)] = 1.0f - 2.0f / (e + 1.0f);
        }
    }
}

extern "C" void kernel_launch(void* const* d_in, const int* in_sizes, int n_in,
                              void* d_out, int out_size, void* d_ws, size_t ws_size,
                              hipStream_t stream) {
    const float* F    = (const float*)d_in[0];  // [32768, 1024] f32
    const float* W    = (const float*)d_in[1];  // [64, 2, 1024] f32
    const float* bias = (const float*)d_in[2];  // [64, 2] f32
    float* outp       = (float*)d_out;          // [2][32768, 64] f32

    const size_t ws_needed = (size_t)N_COLS * L_DIM * sizeof(__bf16);  // 256 KB

    if (ws_size >= ws_needed) {
        bf16x8* wf = (bf16x8*)d_ws;
        hipLaunchKernelGGL(convert_w_kernel, dim3(64), dim3(256), 0, stream, W, wf);
        hipLaunchKernelGGL(branched_policy_kernel, dim3(B_DIM / 64), dim3(512), 0, stream,
                           F, (const float4*)wf, bias, outp);
    } else {
        hipLaunchKernelGGL(fallback_kernel, dim3(B_DIM / 64), dim3(256), 0, stream,
                           F, W, bias, outp);
    }
}

// Round 7
// 37.838 us; speedup vs baseline: 2.2947x; 2.2947x over previous
//
#include <hip/hip_runtime.h>
#include <hip/hip_bf16.h>

// Problem constants
#define B_DIM   32768
#define A_DIM   64
#define L_DIM   1024          // K
#define N_COLS  128           // 2*A

using bf16x8 = __attribute__((ext_vector_type(8))) __bf16;
using f32x4  = __attribute__((ext_vector_type(4))) float;

// global -> LDS direct (16B per lane; LDS dest = wave-uniform base + lane*16)
#define GLL16(g, l)                                                            \
    __builtin_amdgcn_global_load_lds(                                          \
        (const __attribute__((address_space(1))) unsigned int*)(g),            \
        (__attribute__((address_space(3))) unsigned int*)(l), 16, 0, 0)

// ---------------------------------------------------------------------------
// Pre-kernel: convert W [128 x 1024] f32 -> bf16 in MFMA B-fragment order.
// Unit v (16B): nl=v&15, sub=(v>>4)&3, cf=(v>>6)&7, ks=(v>>9)&31
//   holds Wm[n = cf*16+nl][k = ks*32 + sub*8 + i], i=0..7
// ---------------------------------------------------------------------------
__global__ __launch_bounds__(256)
void convert_w_kernel(const float* __restrict__ W, bf16x8* __restrict__ ws) {
    int v   = blockIdx.x * 256 + threadIdx.x;   // 0..16383
    int nl  = v & 15;
    int sub = (v >> 4) & 3;
    int cf  = (v >> 6) & 7;
    int ks  = (v >> 9) & 31;
    int n   = cf * 16 + nl;
    int k   = ks * 32 + sub * 8;
    const float4* wp = (const float4*)(W + (size_t)n * L_DIM + k);
    float4 w0 = wp[0];
    float4 w1 = wp[1];
    bf16x8 u;
    u[0] = (__bf16)w0.x; u[1] = (__bf16)w0.y;
    u[2] = (__bf16)w0.z; u[3] = (__bf16)w0.w;
    u[4] = (__bf16)w1.x; u[5] = (__bf16)w1.y;
    u[6] = (__bf16)w1.z; u[7] = (__bf16)w1.w;
    ws[v] = u;
}

__device__ __forceinline__ bf16x8 cvt8(float4 a, float4 b) {
    bf16x8 u;
    u[0] = (__bf16)a.x; u[1] = (__bf16)a.y; u[2] = (__bf16)a.z; u[3] = (__bf16)a.w;
    u[4] = (__bf16)b.x; u[5] = (__bf16)b.y; u[6] = (__bf16)b.z; u[7] = (__bf16)b.w;
    return u;
}

// ---------------------------------------------------------------------------
// Main kernel (split-K): 512 threads = 8 waves = 4 row-tiles x 2 k-halves.
// Block covers 64 rows x full K. Grid = 512 -> 2 blocks/CU -> 16 waves/CU.
// Wave (h, r): rows [blk*64 + r*16, +16), k in [h*512, +512), all 128 cols.
// B (bf16 fragment order in ws) staged per phase (4 k-steps, 32 KB/half)
// via global_load_lds — zero VGPR footprint, nothing live across barriers.
// All LDS traffic lane-contiguous -> 0 bank conflicts.
// Split-K combine in-block through retired LDS.
// ---------------------------------------------------------------------------
__global__ __launch_bounds__(512, 4)
void branched_policy_kernel(const float* __restrict__ F,
                            const float4* __restrict__ Wf,
                            const float* __restrict__ bias,
                            float* __restrict__ out) {
    __shared__ float4 ldsB[2][2048];   // 2 halves x 32 KB (one phase each)

    const int tid  = threadIdx.x;
    const int lane = tid & 63;
    const int wave = tid >> 6;        // 0..7
    const int h    = wave >> 2;       // k-half 0/1
    const int r    = wave & 3;        // row-tile 0..3
    const int lcol = lane & 15;       // fragment row (A) / col (B)
    const int lsub = lane >> 4;       // k subgroup 0..3
    const int blk  = blockIdx.x;

    const float* fp = F + (size_t)(blk * 64 + r * 16 + lcol) * L_DIM
                        + h * 512 + lsub * 8;
    const float4* wsrc = Wf + h * 8192 + lane;   // + p*2048 + c*64

    f32x4 acc[8];
    #pragma unroll
    for (int cf = 0; cf < 8; ++cf) acc[cf] = (f32x4){0.f, 0.f, 0.f, 0.f};

    #pragma unroll
    for (int p = 0; p < 4; ++p) {
        __syncthreads();               // prev phase's ds_reads retired
        // stage B phase p: 32 chunks/half, 8 per wave, lane-contiguous
        #pragma unroll
        for (int i = 0; i < 8; ++i) {
            int c = i * 4 + r;
            GLL16(wsrc + p * 2048 + c * 64, &ldsB[h][c * 64]);
        }
        __syncthreads();               // barrier drains vmcnt -> B arrived

        // compute 4 k-steps of this phase
        #pragma unroll
        for (int j = 0; j < 4; ++j) {
            int kk = p * 4 + j;
            float4 a0 = *(const float4*)(fp + kk * 32);
            float4 a1 = *(const float4*)(fp + kk * 32 + 4);
            bf16x8 af = cvt8(a0, a1);
            #pragma unroll
            for (int cf = 0; cf < 8; ++cf) {
                bf16x8 bf = *(const bf16x8*)&ldsB[h][(j * 8 + cf) * 64 + lane];
                acc[cf] = __builtin_amdgcn_mfma_f32_16x16x32_bf16(af, bf, acc[cf], 0, 0, 0);
            }
        }
    }

    // ---- split-K combine + epilogue ----
    __syncthreads();                   // all compute ds_reads retired
    f32x4* red = (f32x4*)&ldsB[0][0];  // 32 KB, reuses retired B space
    if (h == 1) {
        #pragma unroll
        for (int cf = 0; cf < 8; ++cf)
            red[(r * 8 + cf) * 64 + lane] = acc[cf];   // lane-contiguous
    }
    __syncthreads();
    if (h == 0) {
        const int row0 = blk * 64 + r * 16 + lsub * 4;
        float* out0 = out;
        float* out1 = out + (size_t)B_DIM * A_DIM;
        #pragma unroll
        for (int cf = 0; cf < 8; ++cf) {
            f32x4 part = red[(r * 8 + cf) * 64 + lane];
            int   n  = cf * 16 + lcol;
            float bv = bias[n];
            float* ob = ((n & 1) ? out1 : out0) + (n >> 1);
            #pragma unroll
            for (int j = 0; j < 4; ++j) {
                float x = acc[cf][j] + part[j] + bv;
                float e = __expf(2.0f * x);             // tanh = 1 - 2/(e^2x+1)
                ob[(size_t)(row0 + j) * A_DIM] = 1.0f - 2.0f / (e + 1.0f);
            }
        }
    }
}

// ---------------------------------------------------------------------------
// Fallback (v1-style, self-contained) if ws is too small.
// ---------------------------------------------------------------------------
__global__ __launch_bounds__(256, 2)
void fallback_kernel(const float* __restrict__ F,
                     const float* __restrict__ W,
                     const float* __restrict__ bias,
                     float* __restrict__ out) {
    __shared__ bf16x8 ldsB[4096];
    const int tid  = threadIdx.x;
    const int lane = tid & 63;
    const int wave = tid >> 6;
    const int blk  = blockIdx.x;
    const int lcol = lane & 15;
    const int lsub = lane >> 4;
    const int arow = blk * 64 + wave * 16 + lcol;
    const float* Fp = F + (size_t)arow * L_DIM + lsub * 8;

    f32x4 acc[8];
    #pragma unroll
    for (int c = 0; c < 8; ++c) acc[c] = (f32x4){0.f, 0.f, 0.f, 0.f};

    for (int ch = 0; ch < 4; ++ch) {
        __syncthreads();
        #pragma unroll
        for (int i = 0; i < 16; ++i) {
            int v   = i * 256 + tid;
            int nl  = v & 15;
            int sub = (v >> 4) & 3;
            int c   = (v >> 6) & 7;
            int ks  = (v >> 9) & 7;
            int nn  = c * 16 + nl;
            int k   = ch * 256 + ks * 32 + sub * 8;
            const float4* wp = (const float4*)(W + (size_t)nn * L_DIM + k);
            ldsB[v] = cvt8(wp[0], wp[1]);
        }
        __syncthreads();
        #pragma unroll
        for (int ks = 0; ks < 8; ++ks) {
            const float4* ap = (const float4*)(Fp + ch * 256 + ks * 32);
            bf16x8 af = cvt8(ap[0], ap[1]);
            #pragma unroll
            for (int c = 0; c < 8; ++c) {
                bf16x8 bf = ldsB[(ks * 8 + c) * 64 + lane];
                acc[c] = __builtin_amdgcn_mfma_f32_16x16x32_bf16(af, bf, acc[c], 0, 0, 0);
            }
        }
    }

    const int orow0 = blk * 64 + wave * 16 + lsub * 4;
    float* out0 = out;
    float* out1 = out + (size_t)B_DIM * A_DIM;
    #pragma unroll
    for (int c = 0; c < 8; ++c) {
        int   nn  = c * 16 + lcol;
        float bvv = bias[nn];
        float* ob = (nn & 1) ? out1 : out0;
        #pragma unroll
        for (int j = 0; j < 4; ++j) {
            float x = acc[c][j] + bvv;
            float e = __expf(2.0f * x);
            ob[(size_t)(orow0 + j) * A_DIM + (nn >> 1)] = 1.0f - 2.0f / (e + 1.0f);
        }
    }
}

extern "C" void kernel_launch(void* const* d_in, const int* in_sizes, int n_in,
                              void* d_out, int out_size, void* d_ws, size_t ws_size,
                              hipStream_t stream) {
    const float* F    = (const float*)d_in[0];  // [32768, 1024] f32
    const float* W    = (const float*)d_in[1];  // [64, 2, 1024] f32
    const float* bias = (const float*)d_in[2];  // [64, 2] f32
    float* outp       = (float*)d_out;          // [2][32768, 64] f32

    const size_t ws_needed = (size_t)N_COLS * L_DIM * sizeof(__bf16);  // 256 KB

    if (ws_size >= ws_needed) {
        bf16x8* wf = (bf16x8*)d_ws;
        hipLaunchKernelGGL(convert_w_kernel, dim3(64), dim3(256), 0, stream, W, wf);
        hipLaunchKernelGGL(branched_policy_kernel, dim3(B_DIM / 64), dim3(512), 0, stream,
                           F, (const float4*)wf, bias, outp);
    } else {
        hipLaunchKernelGGL(fallback_kernel, dim3(B_DIM / 64), dim3(256), 0, stream,
                           F, W, bias, outp);
    }
}

// Round 8
// 37.628 us; speedup vs baseline: 2.3075x; 1.0056x over previous
//
#include <hip/hip_runtime.h>
#include <hip/hip_bf16.h>

// Problem constants
#define B_DIM   32768
#define A_DIM   64
#define L_DIM   1024          // K
#define N_COLS  128           // 2*A

using bf16x8 = __attribute__((ext_vector_type(8))) __bf16;
using f32x4  = __attribute__((ext_vector_type(4))) float;

// global -> LDS direct (16B per lane; LDS dest = wave-uniform base + lane*16)
#define GLL16(g, l)                                                            \
    __builtin_amdgcn_global_load_lds(                                          \
        (const __attribute__((address_space(1))) unsigned int*)(g),            \
        (__attribute__((address_space(3))) unsigned int*)(l), 16, 0, 0)

// ---------------------------------------------------------------------------
// Pre-kernel: convert W [128 x 1024] f32 -> bf16 in MFMA B-fragment order.
// Unit v (16B): nl=v&15, sub=(v>>4)&3, cf=(v>>6)&7, ks=(v>>9)&31
//   holds Wm[n = cf*16+nl][k = ks*32 + sub*8 + i], i=0..7
// ---------------------------------------------------------------------------
__global__ __launch_bounds__(256)
void convert_w_kernel(const float* __restrict__ W, bf16x8* __restrict__ ws) {
    int v   = blockIdx.x * 256 + threadIdx.x;   // 0..16383
    int nl  = v & 15;
    int sub = (v >> 4) & 3;
    int cf  = (v >> 6) & 7;
    int ks  = (v >> 9) & 31;
    int n   = cf * 16 + nl;
    int k   = ks * 32 + sub * 8;
    const float4* wp = (const float4*)(W + (size_t)n * L_DIM + k);
    float4 w0 = wp[0];
    float4 w1 = wp[1];
    bf16x8 u;
    u[0] = (__bf16)w0.x; u[1] = (__bf16)w0.y;
    u[2] = (__bf16)w0.z; u[3] = (__bf16)w0.w;
    u[4] = (__bf16)w1.x; u[5] = (__bf16)w1.y;
    u[6] = (__bf16)w1.z; u[7] = (__bf16)w1.w;
    ws[v] = u;
}

__device__ __forceinline__ bf16x8 cvt8(float4 a, float4 b) {
    bf16x8 u;
    u[0] = (__bf16)a.x; u[1] = (__bf16)a.y; u[2] = (__bf16)a.z; u[3] = (__bf16)a.w;
    u[4] = (__bf16)b.x; u[5] = (__bf16)b.y; u[6] = (__bf16)b.z; u[7] = (__bf16)b.w;
    return u;
}

// ---------------------------------------------------------------------------
// Main kernel: 512 threads = 8 waves; wave owns 16 rows x full K; block =
// 128 rows; grid = 256 = 1 block/CU. B (bf16 fragment order) staged per
// half-K (128 KB static LDS) via global_load_lds; only 3 barriers total.
// A-path: explicit two-buffer register pipeline — while chunk c (4 k-steps)
// computes, chunk c+1's 8 float4 loads are issued interleaved. No barrier
// ever interrupts the A stream except the single mid-kernel B restage.
// All LDS traffic lane-contiguous -> 0 bank conflicts.
// ---------------------------------------------------------------------------
__global__ __launch_bounds__(512, 2)
void branched_policy_kernel(const float* __restrict__ F,
                            const float4* __restrict__ Wf,
                            const float* __restrict__ bias,
                            float* __restrict__ out) {
    __shared__ float4 ldsB[8192];     // 128 KB = one half-K of B fragments

    const int tid  = threadIdx.x;
    const int lane = tid & 63;
    const int wave = tid >> 6;        // 0..7
    const int blk  = blockIdx.x;
    const int lcol = lane & 15;       // fragment row (A) / col (B)
    const int lsub = lane >> 4;       // k subgroup 0..3

    const float* fp = F + (size_t)(blk * 128 + wave * 16 + lcol) * L_DIM
                        + lsub * 8;

    f32x4 acc[8];
    #pragma unroll
    for (int cf = 0; cf < 8; ++cf) acc[cf] = (f32x4){0.f, 0.f, 0.f, 0.f};

    // ---- prologue: issue A chunk 0 first (overlaps B staging latency) ----
    float4 raw[2][4][2];
    #pragma unroll
    for (int j = 0; j < 4; ++j) {
        raw[0][j][0] = *(const float4*)(fp + j * 32);
        raw[0][j][1] = *(const float4*)(fp + j * 32 + 4);
    }

    // ---- stage B half 0 (ks 0..15): gll, lane-contiguous ----
    #pragma unroll
    for (int i = 0; i < 16; ++i)
        GLL16(Wf + i * 512 + tid, &ldsB[i * 512 + tid]);
    __syncthreads();

    // ---- main loop: 8 chunks of 4 k-steps ----
    #pragma unroll
    for (int c = 0; c < 8; ++c) {
        constexpr int CUR_OF[8] = {0, 1, 0, 1, 0, 1, 0, 1};
        const int cur = CUR_OF[c & 7];
        const int nxt = cur ^ 1;

        if (c == 4) {
            __syncthreads();          // all waves done reading half 0
            #pragma unroll
            for (int i = 0; i < 16; ++i)
                GLL16(Wf + 8192 + i * 512 + tid, &ldsB[i * 512 + tid]);
            __syncthreads();          // half 1 arrived
        }

        #pragma unroll
        for (int j = 0; j < 4; ++j) {
            if (c + 1 < 8) {          // issue next chunk's A loads
                int kk = (c + 1) * 4 + j;
                raw[nxt][j][0] = *(const float4*)(fp + kk * 32);
                raw[nxt][j][1] = *(const float4*)(fp + kk * 32 + 4);
            }
            bf16x8 af = cvt8(raw[cur][j][0], raw[cur][j][1]);
            int ks = (c & 3) * 4 + j;                 // kstep within half
            #pragma unroll
            for (int cf = 0; cf < 8; ++cf) {
                bf16x8 bf = *(const bf16x8*)&ldsB[(ks * 8 + cf) * 64 + lane];
                acc[cf] = __builtin_amdgcn_mfma_f32_16x16x32_bf16(af, bf, acc[cf], 0, 0, 0);
            }
        }
    }

    // ---- epilogue: bias + tanh + de-interleave ----
    const int row0 = blk * 128 + wave * 16 + lsub * 4;
    float* out0 = out;
    float* out1 = out + (size_t)B_DIM * A_DIM;
    #pragma unroll
    for (int cf = 0; cf < 8; ++cf) {
        int   n  = cf * 16 + lcol;
        float bv = bias[n];
        float* ob = ((n & 1) ? out1 : out0) + (n >> 1);
        #pragma unroll
        for (int j = 0; j < 4; ++j) {
            float x = acc[cf][j] + bv;
            float e = __expf(2.0f * x);               // tanh = 1 - 2/(e^2x+1)
            ob[(size_t)(row0 + j) * A_DIM] = 1.0f - 2.0f / (e + 1.0f);
        }
    }
}

// ---------------------------------------------------------------------------
// Fallback (v1-style, self-contained) if ws is too small.
// ---------------------------------------------------------------------------
__global__ __launch_bounds__(256, 2)
void fallback_kernel(const float* __restrict__ F,
                     const float* __restrict__ W,
                     const float* __restrict__ bias,
                     float* __restrict__ out) {
    __shared__ bf16x8 ldsB[4096];
    const int tid  = threadIdx.x;
    const int lane = tid & 63;
    const int wave = tid >> 6;
    const int blk  = blockIdx.x;
    const int lcol = lane & 15;
    const int lsub = lane >> 4;
    const int arow = blk * 64 + wave * 16 + lcol;
    const float* Fp = F + (size_t)arow * L_DIM + lsub * 8;

    f32x4 acc[8];
    #pragma unroll
    for (int c = 0; c < 8; ++c) acc[c] = (f32x4){0.f, 0.f, 0.f, 0.f};

    for (int ch = 0; ch < 4; ++ch) {
        __syncthreads();
        #pragma unroll
        for (int i = 0; i < 16; ++i) {
            int v   = i * 256 + tid;
            int nl  = v & 15;
            int sub = (v >> 4) & 3;
            int c   = (v >> 6) & 7;
            int ks  = (v >> 9) & 7;
            int nn  = c * 16 + nl;
            int k   = ch * 256 + ks * 32 + sub * 8;
            const float4* wp = (const float4*)(W + (size_t)nn * L_DIM + k);
            ldsB[v] = cvt8(wp[0], wp[1]);
        }
        __syncthreads();
        #pragma unroll
        for (int ks = 0; ks < 8; ++ks) {
            const float4* ap = (const float4*)(Fp + ch * 256 + ks * 32);
            bf16x8 af = cvt8(ap[0], ap[1]);
            #pragma unroll
            for (int c = 0; c < 8; ++c) {
                bf16x8 bf = ldsB[(ks * 8 + c) * 64 + lane];
                acc[c] = __builtin_amdgcn_mfma_f32_16x16x32_bf16(af, bf, acc[c], 0, 0, 0);
            }
        }
    }

    const int orow0 = blk * 64 + wave * 16 + lsub * 4;
    float* out0 = out;
    float* out1 = out + (size_t)B_DIM * A_DIM;
    #pragma unroll
    for (int c = 0; c < 8; ++c) {
        int   nn  = c * 16 + lcol;
        float bvv = bias[nn];
        float* ob = (nn & 1) ? out1 : out0;
        #pragma unroll
        for (int j = 0; j < 4; ++j) {
            float x = acc[c][j] + bvv;
            float e = __expf(2.0f * x);
            ob[(size_t)(orow0 + j) * A_DIM + (nn >> 1)] = 1.0f - 2.0f / (e + 1.0f);
        }
    }
}

extern "C" void kernel_launch(void* const* d_in, const int* in_sizes, int n_in,
                              void* d_out, int out_size, void* d_ws, size_t ws_size,
                              hipStream_t stream) {
    const float* F    = (const float*)d_in[0];  // [32768, 1024] f32
    const float* W    = (const float*)d_in[1];  // [64, 2, 1024] f32
    const float* bias = (const float*)d_in[2];  // [64, 2] f32
    float* outp       = (float*)d_out;          // [2][32768, 64] f32

    const size_t ws_needed = (size_t)N_COLS * L_DIM * sizeof(__bf16);  // 256 KB

    if (ws_size >= ws_needed) {
        bf16x8* wf = (bf16x8*)d_ws;
        hipLaunchKernelGGL(convert_w_kernel, dim3(64), dim3(256), 0, stream, W, wf);
        hipLaunchKernelGGL(branched_policy_kernel, dim3(B_DIM / 128), dim3(512), 0, stream,
                           F, (const float4*)wf, bias, outp);
    } else {
        hipLaunchKernelGGL(fallback_kernel, dim3(B_DIM / 64), dim3(256), 0, stream,
                           F, W, bias, outp);
    }
}